// Round 1
// baseline (252.049 us; speedup 1.0000x reference)
//
#include <hip/hip_runtime.h>
#include <math.h>

#define BATCH 4
#define SEQ   1024
#define DIN   512
#define DKQ   512
#define DV    64
#define NH    64
#define HD    8    // per-head q/k dim

// ---------------------------------------------------------------------------
// Projection GEMM: C = relu(x @ W + bias), written head-major.
//   z=0: Q (N=512) -> Qh[((b*64+h)*1024+s)*8+d]
//   z=1: K (N=512) -> Kh same layout
//   z=2: V (N=64)  -> Vh[(b*64+h)*1024+s]
// BM=128, BN=64, BK=16, 256 threads, 8x4 micro-tile.
// ---------------------------------------------------------------------------
__global__ __launch_bounds__(256)
void proj_kernel(const float* __restrict__ x,
                 const float* __restrict__ Wq, const float* __restrict__ bq,
                 const float* __restrict__ Wk, const float* __restrict__ bk,
                 const float* __restrict__ Wv, const float* __restrict__ bv,
                 float* __restrict__ Qh, float* __restrict__ Kh,
                 float* __restrict__ Vh)
{
    const int z = blockIdx.z;
    const int N = (z == 2) ? DV : DKQ;
    if (z == 2 && blockIdx.x != 0) return;   // V only has one 64-col tile

    const float* __restrict__ W    = (z == 0) ? Wq : (z == 1) ? Wk : Wv;
    const float* __restrict__ bias = (z == 0) ? bq : (z == 1) ? bk : bv;

    __shared__ float As[16][128];   // A tile, transposed: As[k][m]
    __shared__ float Bs[16][64];    // B tile: Bs[k][n]

    const int t  = threadIdx.x;
    const int bm = blockIdx.y * 128;
    const int bn = blockIdx.x * 64;
    const int tm = t >> 4;          // 0..15 -> 8 rows each
    const int tn = t & 15;          // 0..15 -> 4 cols each

    // load assignments
    const int ar = t >> 1;          // 0..127 (A row within tile)
    const int ac = (t & 1) * 8;     // 0 or 8 (A col group)
    const int br = t >> 4;          // 0..15  (B row within tile)
    const int bc = (t & 15) * 4;    // 0..60  (B col group)

    float acc[8][4] = {};

    for (int k0 = 0; k0 < DIN; k0 += 16) {
        // prefetch to registers before the barrier
        const float* ap = &x[(size_t)(bm + ar) * DIN + k0 + ac];
        float4 a0 = *(const float4*)(ap);
        float4 a1 = *(const float4*)(ap + 4);
        float4 b0 = *(const float4*)&W[(size_t)(k0 + br) * N + bn + bc];

        __syncthreads();   // previous iteration's reads done
        As[ac + 0][ar] = a0.x; As[ac + 1][ar] = a0.y;
        As[ac + 2][ar] = a0.z; As[ac + 3][ar] = a0.w;
        As[ac + 4][ar] = a1.x; As[ac + 5][ar] = a1.y;
        As[ac + 6][ar] = a1.z; As[ac + 7][ar] = a1.w;
        *(float4*)&Bs[br][bc] = b0;
        __syncthreads();

        #pragma unroll
        for (int kk = 0; kk < 16; ++kk) {
            float4 av0 = *(const float4*)&As[kk][tm * 8];
            float4 av1 = *(const float4*)&As[kk][tm * 8 + 4];
            float4 bv4 = *(const float4*)&Bs[kk][tn * 4];
            float aa[8] = {av0.x, av0.y, av0.z, av0.w, av1.x, av1.y, av1.z, av1.w};
            float bb[4] = {bv4.x, bv4.y, bv4.z, bv4.w};
            #pragma unroll
            for (int i = 0; i < 8; ++i)
                #pragma unroll
                for (int j = 0; j < 4; ++j)
                    acc[i][j] = fmaf(aa[i], bb[j], acc[i][j]);
        }
    }

    // epilogue: bias + relu + head-major store
    #pragma unroll
    for (int i = 0; i < 8; ++i) {
        const int row = bm + tm * 8 + i;
        const int b = row >> 10, s = row & 1023;
        #pragma unroll
        for (int j = 0; j < 4; ++j) {
            const int c = bn + tn * 4 + j;
            float v = fmaxf(acc[i][j] + bias[c], 0.0f);
            if (z == 2) {
                Vh[(size_t)(b * NH + c) * SEQ + s] = v;
            } else {
                float* outp = (z == 0) ? Qh : Kh;
                const int h = c >> 3, d = c & 7;
                outp[((size_t)(b * NH + h) * SEQ + s) * HD + d] = v;
            }
        }
    }
}

// ---------------------------------------------------------------------------
// Attention: one block per (b, h, half). K/V head-tiles in LDS (broadcast
// reads), 2 q rows per thread in registers, online exp-sum (no max needed:
// scores bounded by ~5, fp32 cannot overflow). dv=1 so PV is a scalar sum.
// ---------------------------------------------------------------------------
__global__ __launch_bounds__(256)
void attn_kernel(const float* __restrict__ Qh, const float* __restrict__ Kh,
                 const float* __restrict__ Vh, float* __restrict__ out)
{
    __shared__ float Ks[SEQ * HD];   // 32 KB
    __shared__ float Vs[SEQ];        //  4 KB

    const int bh   = blockIdx.x;     // 0..255 = b*64 + h
    const int half = blockIdx.y;     // 0..1
    const int b = bh >> 6, h = bh & 63;
    const float* __restrict__ qp = Qh + (size_t)bh * SEQ * HD;
    const float* __restrict__ kp = Kh + (size_t)bh * SEQ * HD;
    const float* __restrict__ vp = Vh + (size_t)bh * SEQ;
    const int t = threadIdx.x;

    for (int i = t; i < SEQ * HD / 4; i += 256)
        ((float4*)Ks)[i] = ((const float4*)kp)[i];
    for (int i = t; i < SEQ / 4; i += 256)
        ((float4*)Vs)[i] = ((const float4*)vp)[i];
    __syncthreads();

    const int r0 = half * 512 + t;   // first q row
    const int r1 = r0 + 256;         // second q row

    float q0[8], q1[8];
    {
        float4 u0 = *(const float4*)&qp[(size_t)r0 * 8];
        float4 u1 = *(const float4*)&qp[(size_t)r0 * 8 + 4];
        float4 w0 = *(const float4*)&qp[(size_t)r1 * 8];
        float4 w1 = *(const float4*)&qp[(size_t)r1 * 8 + 4];
        q0[0]=u0.x; q0[1]=u0.y; q0[2]=u0.z; q0[3]=u0.w;
        q0[4]=u1.x; q0[5]=u1.y; q0[6]=u1.z; q0[7]=u1.w;
        q1[0]=w0.x; q1[1]=w0.y; q1[2]=w0.z; q1[3]=w0.w;
        q1[4]=w1.x; q1[5]=w1.y; q1[6]=w1.z; q1[7]=w1.w;
    }

    // scale/sqrt(8) folded with log2(e) so exp is a single v_exp_f32
    const float c = 0.35355339059327373f * 1.4426950408889634f;

    float l0 = 0.f, l1 = 0.f, a0 = 0.f, a1 = 0.f;

    #pragma unroll 4
    for (int k = 0; k < SEQ; ++k) {
        const float* kr = &Ks[k * HD];          // wave-uniform -> broadcast
        float4 ka = *(const float4*)kr;
        float4 kb = *(const float4*)(kr + 4);
        float v = Vs[k];
        float s0 = q0[0]*ka.x + q0[1]*ka.y + q0[2]*ka.z + q0[3]*ka.w
                 + q0[4]*kb.x + q0[5]*kb.y + q0[6]*kb.z + q0[7]*kb.w;
        float s1 = q1[0]*ka.x + q1[1]*ka.y + q1[2]*ka.z + q1[3]*ka.w
                 + q1[4]*kb.x + q1[5]*kb.y + q1[6]*kb.z + q1[7]*kb.w;
        float p0 = exp2f(s0 * c);
        float p1 = exp2f(s1 * c);
        l0 += p0; a0 = fmaf(p0, v, a0);
        l1 += p1; a1 = fmaf(p1, v, a1);
    }

    // positional embedding: cos block (h<32) then sin block, freq 10000^(-j/32)
    const int j = h & 31;
    const float fr = exp2f((float)j * -0.4152410118609203f); // -log2(10000)/32
    const float pe0 = (h < 32) ? cosf((float)r0 * fr) : sinf((float)r0 * fr);
    const float pe1 = (h < 32) ? cosf((float)r1 * fr) : sinf((float)r1 * fr);

    out[(size_t)(b * SEQ + r0) * DV + h] = a0 / l0 + pe0;
    out[(size_t)(b * SEQ + r1) * DV + h] = a1 / l1 + pe1;
}

// ---------------------------------------------------------------------------
extern "C" void kernel_launch(void* const* d_in, const int* in_sizes, int n_in,
                              void* d_out, int out_size, void* d_ws, size_t ws_size,
                              hipStream_t stream)
{
    const float* x  = (const float*)d_in[0];
    const float* Wq = (const float*)d_in[1];
    const float* bq = (const float*)d_in[2];
    const float* Wk = (const float*)d_in[3];
    const float* bk = (const float*)d_in[4];
    const float* Wv = (const float*)d_in[5];
    const float* bv = (const float*)d_in[6];
    float* out = (float*)d_out;

    // workspace layout (floats): Qh[4*64*1024*8] | Kh[same] | Vh[4*64*1024]
    float* Qh = (float*)d_ws;
    float* Kh = Qh + (size_t)BATCH * NH * SEQ * HD;
    float* Vh = Kh + (size_t)BATCH * NH * SEQ * HD;

    dim3 pgrid(DKQ / 64, (BATCH * SEQ) / 128, 3);
    proj_kernel<<<pgrid, 256, 0, stream>>>(x, Wq, bq, Wk, bk, Wv, bv, Qh, Kh, Vh);

    attn_kernel<<<dim3(BATCH * NH, 2), 256, 0, stream>>>(Qh, Kh, Vh, out);
}

// Round 2
// 185.294 us; speedup vs baseline: 1.3603x; 1.3603x over previous
//
#include <hip/hip_runtime.h>
#include <math.h>

#define BATCH 4
#define SEQ   1024
#define DIN   512
#define DKQ   512
#define DV    64
#define NH    64
#define HD    8    // per-head q/k dim

typedef __attribute__((ext_vector_type(8))) short short8v;   // 8 bf16 in 4 VGPRs
typedef __attribute__((ext_vector_type(4))) float float4v;

// round-to-nearest-even float -> bf16 bits (finite inputs only)
__device__ __forceinline__ unsigned short f32_to_bf16_rne(float f) {
    unsigned int u = __float_as_uint(f);
    u += 0x7FFFu + ((u >> 16) & 1u);
    return (unsigned short)(u >> 16);
}
__device__ __forceinline__ float bf16_bits_to_f32(unsigned short s) {
    return __uint_as_float((unsigned int)s << 16);
}

// ---------------------------------------------------------------------------
// Projection GEMM: C = relu(x @ W + bias).
//   z=0: Q -> Qpk[bh][s][0..7]=bf16_hi, [8..15]=bf16_lo   (ushort)
//   z=1: K -> Kpk same layout
//   z=2: V -> Vh[bh][s]  (fp32)
// BM=128, BN=64, BK=16, 256 threads, 8x4 micro-tile. (unchanged main loop)
// ---------------------------------------------------------------------------
__global__ __launch_bounds__(256)
void proj_kernel(const float* __restrict__ x,
                 const float* __restrict__ Wq, const float* __restrict__ bq,
                 const float* __restrict__ Wk, const float* __restrict__ bk,
                 const float* __restrict__ Wv, const float* __restrict__ bv,
                 unsigned short* __restrict__ Qpk, unsigned short* __restrict__ Kpk,
                 float* __restrict__ Vh)
{
    const int z = blockIdx.z;
    const int N = (z == 2) ? DV : DKQ;
    if (z == 2 && blockIdx.x != 0) return;

    const float* __restrict__ W    = (z == 0) ? Wq : (z == 1) ? Wk : Wv;
    const float* __restrict__ bias = (z == 0) ? bq : (z == 1) ? bk : bv;

    __shared__ float As[16][128];
    __shared__ float Bs[16][64];

    const int t  = threadIdx.x;
    const int bm = blockIdx.y * 128;
    const int bn = blockIdx.x * 64;
    const int tm = t >> 4;
    const int tn = t & 15;

    const int ar = t >> 1;
    const int ac = (t & 1) * 8;
    const int br = t >> 4;
    const int bc = (t & 15) * 4;

    float acc[8][4] = {};

    for (int k0 = 0; k0 < DIN; k0 += 16) {
        const float* ap = &x[(size_t)(bm + ar) * DIN + k0 + ac];
        float4 a0 = *(const float4*)(ap);
        float4 a1 = *(const float4*)(ap + 4);
        float4 b0 = *(const float4*)&W[(size_t)(k0 + br) * N + bn + bc];

        __syncthreads();
        As[ac + 0][ar] = a0.x; As[ac + 1][ar] = a0.y;
        As[ac + 2][ar] = a0.z; As[ac + 3][ar] = a0.w;
        As[ac + 4][ar] = a1.x; As[ac + 5][ar] = a1.y;
        As[ac + 6][ar] = a1.z; As[ac + 7][ar] = a1.w;
        *(float4*)&Bs[br][bc] = b0;
        __syncthreads();

        #pragma unroll
        for (int kk = 0; kk < 16; ++kk) {
            float4 av0 = *(const float4*)&As[kk][tm * 8];
            float4 av1 = *(const float4*)&As[kk][tm * 8 + 4];
            float4 bv4 = *(const float4*)&Bs[kk][tn * 4];
            float aa[8] = {av0.x, av0.y, av0.z, av0.w, av1.x, av1.y, av1.z, av1.w};
            float bb[4] = {bv4.x, bv4.y, bv4.z, bv4.w};
            #pragma unroll
            for (int i = 0; i < 8; ++i)
                #pragma unroll
                for (int j = 0; j < 4; ++j)
                    acc[i][j] = fmaf(aa[i], bb[j], acc[i][j]);
        }
    }

    #pragma unroll
    for (int i = 0; i < 8; ++i) {
        const int row = bm + tm * 8 + i;
        const int b = row >> 10, s = row & 1023;
        #pragma unroll
        for (int j = 0; j < 4; ++j) {
            const int c = bn + tn * 4 + j;
            float v = fmaxf(acc[i][j] + bias[c], 0.0f);
            if (z == 2) {
                Vh[(size_t)(b * NH + c) * SEQ + s] = v;
            } else {
                unsigned short hi = f32_to_bf16_rne(v);
                unsigned short lo = f32_to_bf16_rne(v - bf16_bits_to_f32(hi));
                unsigned short* dst = (z == 0) ? Qpk : Kpk;
                const int h = c >> 3, d = c & 7;
                size_t base = ((size_t)(b * NH + h) * SEQ + s) * 16 + d;
                dst[base]     = hi;
                dst[base + 8] = lo;
            }
        }
    }
}

// ---------------------------------------------------------------------------
// Attention via MFMA 16x16x32 bf16 with packed hi/lo fp32 compensation:
//   A k-slots: [q_hi | q_lo | q_hi | 0], B k-slots: [k_hi | k_hi | k_lo | *]
//   => C = q_hi.k_hi + q_lo.k_hi + q_hi.k_lo  (~fp32 exact)
// Block = (b*64+h, quarter). 4 waves/block, each wave owns 64 q rows
// (4 M-tiles). No LDS: per-head K/V (36KB) is L1/L2-resident.
// dv=1: PV = per-lane {l += p, a += p*v} on C fragments, 16-lane reduce.
// ---------------------------------------------------------------------------
__global__ __launch_bounds__(256)
void attn_kernel(const unsigned short* __restrict__ Qpk,
                 const unsigned short* __restrict__ Kpk,
                 const float* __restrict__ Vh, float* __restrict__ out)
{
    const int bh = blockIdx.x;             // b*64 + h
    const int quarter = blockIdx.y;        // 0..3
    const int b = bh >> 6, h = bh & 63;
    const int t = threadIdx.x;
    const int wave = t >> 6, lane = t & 63;
    const int g = lane >> 4, cl = lane & 15;

    const unsigned short* __restrict__ qbase = Qpk + (size_t)bh * SEQ * 16;
    const unsigned short* __restrict__ kbase = Kpk + (size_t)bh * SEQ * 16;
    const float* __restrict__ vbase = Vh + (size_t)bh * SEQ;

    const int m0w = quarter * 256 + wave * 64;

    // A fragments for this wave's 4 M-tiles (row = lane&15, k-group = lane>>4)
    short8v a[4];
    #pragma unroll
    for (int mt = 0; mt < 4; ++mt) {
        if (g == 3) {
            short8v zz = {0,0,0,0,0,0,0,0};
            a[mt] = zz;
        } else {
            const int rowA = m0w + mt * 16 + cl;
            const int off = (g == 1) ? 8 : 0;    // g0,g2 -> hi; g1 -> lo
            a[mt] = *(const short8v*)(qbase + (size_t)rowA * 16 + off);
        }
    }

    float lsum[4][4] = {};
    float asum[4][4] = {};
    const float cc = 0.35355339059327373f * 1.4426950408889634f; // scale*log2e
    const float4v c0 = {0.0f, 0.0f, 0.0f, 0.0f};

    for (int nt = 0; nt < 64; ++nt) {
        const int coln = nt * 16 + cl;
        const int boff = (g == 2) ? 8 : 0;       // g0,g1 -> hi; g2 -> lo; g3 dup hi (x0)
        short8v bf = *(const short8v*)(kbase + (size_t)coln * 16 + boff);
        float v = vbase[coln];
        #pragma unroll
        for (int mt = 0; mt < 4; ++mt) {
            float4v c = __builtin_amdgcn_mfma_f32_16x16x32_bf16(a[mt], bf, c0, 0, 0, 0);
            #pragma unroll
            for (int r = 0; r < 4; ++r) {
                float p = exp2f(c[r] * cc);
                lsum[mt][r] += p;
                asum[mt][r] = fmaf(p, v, asum[mt][r]);
            }
        }
    }

    // positional embedding params
    const float fr = exp2f((float)(h & 31) * -0.4152410118609203f); // 10000^(-j/32)

    // reduce each (mt,r) over the 16 lanes of the group; lane cl==r stores
    #pragma unroll
    for (int mt = 0; mt < 4; ++mt) {
        #pragma unroll
        for (int r = 0; r < 4; ++r) {
            float ls = lsum[mt][r], as = asum[mt][r];
            ls += __shfl_xor(ls, 1);  as += __shfl_xor(as, 1);
            ls += __shfl_xor(ls, 2);  as += __shfl_xor(as, 2);
            ls += __shfl_xor(ls, 4);  as += __shfl_xor(as, 4);
            ls += __shfl_xor(ls, 8);  as += __shfl_xor(as, 8);
            if (cl == r) {
                const int row = m0w + mt * 16 + g * 4 + r;  // C row = (lane>>4)*4+reg
                const float pe = (h < 32) ? cosf((float)row * fr)
                                          : sinf((float)row * fr);
                out[((size_t)b * SEQ + row) * DV + h] = as / ls + pe;
            }
        }
    }
}

// ---------------------------------------------------------------------------
extern "C" void kernel_launch(void* const* d_in, const int* in_sizes, int n_in,
                              void* d_out, int out_size, void* d_ws, size_t ws_size,
                              hipStream_t stream)
{
    const float* x  = (const float*)d_in[0];
    const float* Wq = (const float*)d_in[1];
    const float* bq = (const float*)d_in[2];
    const float* Wk = (const float*)d_in[3];
    const float* bk = (const float*)d_in[4];
    const float* Wv = (const float*)d_in[5];
    const float* bv = (const float*)d_in[6];
    float* out = (float*)d_out;

    // ws layout: Qpk (8MB ushort) | Kpk (8MB ushort) | Vh (1MB float)
    unsigned short* Qpk = (unsigned short*)d_ws;
    unsigned short* Kpk = Qpk + (size_t)BATCH * NH * SEQ * 16;
    float*          Vh  = (float*)(Kpk + (size_t)BATCH * NH * SEQ * 16);

    dim3 pgrid(DKQ / 64, (BATCH * SEQ) / 128, 3);
    proj_kernel<<<pgrid, 256, 0, stream>>>(x, Wq, bq, Wk, bk, Wv, bv, Qpk, Kpk, Vh);

    attn_kernel<<<dim3(BATCH * NH, 4), 256, 0, stream>>>(Qpk, Kpk, Vh, out);
}

// Round 3
// 117.831 us; speedup vs baseline: 2.1391x; 1.5725x over previous
//
#include <hip/hip_runtime.h>
#include <math.h>

#define BATCH 4
#define SEQ   1024
#define DIN   512
#define DKQ   512
#define DV    64
#define NH    64
#define HD    8

typedef __attribute__((ext_vector_type(8))) short short8v;   // 8 bf16 in 4 VGPRs
typedef __attribute__((ext_vector_type(4))) float float4v;

// cheap exact split: f = hi + lo (hi = truncated bf16, lo = bf16 of remainder)
__device__ __forceinline__ void split_bf16(float f, unsigned short& hi, unsigned short& lo) {
    unsigned int u = __float_as_uint(f);
    hi = (unsigned short)(u >> 16);
    float l = f - __uint_as_float(u & 0xFFFF0000u);
    lo = (unsigned short)(__float_as_uint(l) >> 16);
}
__device__ __forceinline__ unsigned short f32_to_bf16_rne(float f) {
    unsigned int u = __float_as_uint(f);
    u += 0x7FFFu + ((u >> 16) & 1u);
    return (unsigned short)(u >> 16);
}
__device__ __forceinline__ float bf16_bits_to_f32(unsigned short s) {
    return __uint_as_float((unsigned int)s << 16);
}

// LDS tile: [row 0..127][slot 0..7][8 bf16], slot XOR-swizzled by row (T2)
__device__ __forceinline__ int ldsoff(int r, int sl) {
    return r * 64 + ((sl ^ (r & 7)) << 3);   // ushort units, 16B-aligned
}

// ---------------------------------------------------------------------------
// W transpose pre-pass: Wt[n][k] = W[k][n]  (rows of Wt are length 512)
// ---------------------------------------------------------------------------
__global__ __launch_bounds__(256)
void transpose_w(const float* __restrict__ Wq, const float* __restrict__ Wk,
                 const float* __restrict__ Wv,
                 float* __restrict__ WtQ, float* __restrict__ WtK,
                 float* __restrict__ WtV)
{
    const int z = blockIdx.z;
    const int N = (z == 2) ? DV : DKQ;
    if (z == 2 && blockIdx.x >= 2) return;
    const float* __restrict__ W  = (z == 0) ? Wq : (z == 1) ? Wk : Wv;
    float* __restrict__ Wt       = (z == 0) ? WtQ : (z == 1) ? WtK : WtV;

    __shared__ float tile[32][33];
    const int n0 = blockIdx.x * 32, k0 = blockIdx.y * 32;
    const int tx = threadIdx.x, ty = threadIdx.y;
    #pragma unroll
    for (int i = 0; i < 32; i += 8)
        tile[ty + i][tx] = W[(size_t)(k0 + ty + i) * N + n0 + tx];
    __syncthreads();
    #pragma unroll
    for (int i = 0; i < 32; i += 8)
        Wt[(size_t)(n0 + ty + i) * DIN + k0 + tx] = tile[tx][ty + i];
}

// ---------------------------------------------------------------------------
// Projection via MFMA 16x16x32 bf16 with hi/lo fp32 compensation:
//   acc += x_hi*w_hi ; acc += x_lo*w_hi ; acc += x_hi*w_lo
// BM=128, BN=128 (V:64), BK=32, 512 threads (8 waves, 2M x 4N).
//   z=0: Q -> Qpk[bh][s][0..7]=hi,[8..15]=lo, pre-scaled by 1/sqrt(8)*log2e
//   z=1: K -> Kpk same layout (unscaled)
//   z=2: V -> Vh[bh][s] fp32
// ---------------------------------------------------------------------------
__global__ __launch_bounds__(512)
void proj_kernel(const float* __restrict__ x,
                 const float* __restrict__ WtQ, const float* __restrict__ bq,
                 const float* __restrict__ WtK, const float* __restrict__ bk,
                 const float* __restrict__ WtV, const float* __restrict__ bv,
                 unsigned short* __restrict__ Qpk, unsigned short* __restrict__ Kpk,
                 float* __restrict__ Vh)
{
    const int z = blockIdx.z;
    if (z == 2 && blockIdx.x != 0) return;
    const float* __restrict__ Wt   = (z == 0) ? WtQ : (z == 1) ? WtK : WtV;
    const float* __restrict__ bias = (z == 0) ? bq : (z == 1) ? bk : bv;

    __shared__ unsigned short As[128 * 64];   // 16 KB
    __shared__ unsigned short Bs[128 * 64];   // 16 KB

    const int t  = threadIdx.x;
    const int bm = blockIdx.y * 128;
    const int bn = blockIdx.x * 128;          // z==2 -> 0

    const int srow = t >> 2;                  // staging row (A) / n-row (B)
    const int sg   = t & 3;                   // staging k-group (8 wide)
    const bool bok = (z != 2) || (srow < 64); // V has only 64 B rows

    const int lane = t & 63, wave = t >> 6;
    const int wr = wave >> 2, wc = wave & 3;  // 2x4 wave grid
    const int cl = lane & 15, g2 = lane >> 4;
    const int NF = (z == 2) ? 1 : 2;          // n-fragments per wave

    float4v acc[4][2];
    #pragma unroll
    for (int i = 0; i < 4; ++i)
        #pragma unroll
        for (int j = 0; j < 2; ++j)
            acc[i][j] = (float4v){0.f, 0.f, 0.f, 0.f};

    for (int ks = 0; ks < 16; ++ks) {
        const int k0 = ks * 32;
        // coalesced fp32 loads (8 floats per thread from x, 8 from Wt)
        const float* ap = &x[(size_t)(bm + srow) * DIN + k0 + sg * 8];
        float4 a0 = *(const float4*)(ap);
        float4 a1 = *(const float4*)(ap + 4);
        float4 b0, b1;
        if (bok) {
            const float* bp = &Wt[(size_t)(bn + srow) * DIN + k0 + sg * 8];
            b0 = *(const float4*)(bp);
            b1 = *(const float4*)(bp + 4);
        }
        short8v ahi, alo, bhi, blo;
        {
            float av[8] = {a0.x, a0.y, a0.z, a0.w, a1.x, a1.y, a1.z, a1.w};
            #pragma unroll
            for (int j = 0; j < 8; ++j) {
                unsigned short h, l; split_bf16(av[j], h, l);
                ahi[j] = (short)h; alo[j] = (short)l;
            }
            if (bok) {
                float bvv[8] = {b0.x, b0.y, b0.z, b0.w, b1.x, b1.y, b1.z, b1.w};
                #pragma unroll
                for (int j = 0; j < 8; ++j) {
                    unsigned short h, l; split_bf16(bvv[j], h, l);
                    bhi[j] = (short)h; blo[j] = (short)l;
                }
            }
        }
        __syncthreads();   // previous iteration's LDS reads complete
        *(short8v*)&As[ldsoff(srow, sg * 2)]     = ahi;
        *(short8v*)&As[ldsoff(srow, sg * 2 + 1)] = alo;
        if (bok) {
            *(short8v*)&Bs[ldsoff(srow, sg * 2)]     = bhi;
            *(short8v*)&Bs[ldsoff(srow, sg * 2 + 1)] = blo;
        }
        __syncthreads();

        short8v af_h[4], af_l[4], bf_h[2], bf_l[2];
        #pragma unroll
        for (int mt = 0; mt < 4; ++mt) {
            const int r = wr * 64 + mt * 16 + cl;
            af_h[mt] = *(const short8v*)&As[ldsoff(r, g2 * 2)];
            af_l[mt] = *(const short8v*)&As[ldsoff(r, g2 * 2 + 1)];
        }
        #pragma unroll
        for (int nf = 0; nf < 2; ++nf) {
            if (nf < NF) {
                const int n = wc * (NF * 16) + nf * 16 + cl;
                bf_h[nf] = *(const short8v*)&Bs[ldsoff(n, g2 * 2)];
                bf_l[nf] = *(const short8v*)&Bs[ldsoff(n, g2 * 2 + 1)];
            }
        }
        #pragma unroll
        for (int mt = 0; mt < 4; ++mt)
            #pragma unroll
            for (int nf = 0; nf < 2; ++nf) {
                if (nf >= NF) continue;
                acc[mt][nf] = __builtin_amdgcn_mfma_f32_16x16x32_bf16(af_h[mt], bf_h[nf], acc[mt][nf], 0, 0, 0);
                acc[mt][nf] = __builtin_amdgcn_mfma_f32_16x16x32_bf16(af_l[mt], bf_h[nf], acc[mt][nf], 0, 0, 0);
                acc[mt][nf] = __builtin_amdgcn_mfma_f32_16x16x32_bf16(af_h[mt], bf_l[nf], acc[mt][nf], 0, 0, 0);
            }
    }

    // epilogue: bias + relu (+Q scale), hi/lo pack or fp32 V store
    const float cc = 0.35355339059327373f * 1.4426950408889634f;
    #pragma unroll
    for (int mt = 0; mt < 4; ++mt) {
        #pragma unroll
        for (int nf = 0; nf < 2; ++nf) {
            if (nf >= NF) continue;
            #pragma unroll
            for (int r = 0; r < 4; ++r) {
                const int row = bm + wr * 64 + mt * 16 + g2 * 4 + r;
                const int b = row >> 10, s = row & 1023;
                if (z == 2) {
                    const int n = wc * 16 + cl;   // head
                    float val = fmaxf(acc[mt][0][r] + bias[n], 0.0f);
                    Vh[(size_t)((b << 6) + n) * SEQ + s] = val;
                } else {
                    const int n = bn + wc * 32 + nf * 16 + cl;
                    float val = fmaxf(acc[mt][nf][r] + bias[n], 0.0f);
                    if (z == 0) val *= cc;
                    const int h = n >> 3, d = n & 7;
                    unsigned short* dst = (z == 0) ? Qpk : Kpk;
                    size_t base = ((size_t)((b << 6) + h) * SEQ + s) * 16 + d;
                    unsigned short hi = f32_to_bf16_rne(val);
                    dst[base]     = hi;
                    dst[base + 8] = f32_to_bf16_rne(val - bf16_bits_to_f32(hi));
                }
            }
        }
    }
}

// ---------------------------------------------------------------------------
// Attention via MFMA 16x16x32 bf16, packed hi/lo compensation (unchanged
// math), Q pre-scaled so p = exp2(c) directly; depth-1 prefetch of B-frag+v.
// ---------------------------------------------------------------------------
__global__ __launch_bounds__(256)
void attn_kernel(const unsigned short* __restrict__ Qpk,
                 const unsigned short* __restrict__ Kpk,
                 const float* __restrict__ Vh, float* __restrict__ out)
{
    const int bh = blockIdx.x;             // b*64 + h
    const int quarter = blockIdx.y;        // 0..3
    const int b = bh >> 6, h = bh & 63;
    const int t = threadIdx.x;
    const int wave = t >> 6, lane = t & 63;
    const int g = lane >> 4, cl = lane & 15;

    const unsigned short* __restrict__ qbase = Qpk + (size_t)bh * SEQ * 16;
    const unsigned short* __restrict__ kbase = Kpk + (size_t)bh * SEQ * 16;
    const float* __restrict__ vbase = Vh + (size_t)bh * SEQ;

    const int m0w = quarter * 256 + wave * 64;

    short8v a[4];
    #pragma unroll
    for (int mt = 0; mt < 4; ++mt) {
        if (g == 3) {
            short8v zz = {0, 0, 0, 0, 0, 0, 0, 0};
            a[mt] = zz;
        } else {
            const int rowA = m0w + mt * 16 + cl;
            const int off = (g == 1) ? 8 : 0;    // g0,g2 -> hi; g1 -> lo
            a[mt] = *(const short8v*)(qbase + (size_t)rowA * 16 + off);
        }
    }

    float lsum[4][4] = {};
    float asum[4][4] = {};
    const float4v c0 = {0.0f, 0.0f, 0.0f, 0.0f};
    const int boff = (g == 2) ? 8 : 0;           // g0,g1 -> hi; g2 -> lo

    short8v bf = *(const short8v*)(kbase + (size_t)cl * 16 + boff);
    float vpre = vbase[cl];

    for (int nt = 0; nt < 64; ++nt) {
        const short8v bcur = bf;
        const float vcur = vpre;
        if (nt < 63) {
            const int c2 = (nt + 1) * 16 + cl;
            bf = *(const short8v*)(kbase + (size_t)c2 * 16 + boff);
            vpre = vbase[c2];
        }
        #pragma unroll
        for (int mt = 0; mt < 4; ++mt) {
            float4v c = __builtin_amdgcn_mfma_f32_16x16x32_bf16(a[mt], bcur, c0, 0, 0, 0);
            #pragma unroll
            for (int r = 0; r < 4; ++r) {
                float p = exp2f(c[r]);            // scale folded into Q
                lsum[mt][r] += p;
                asum[mt][r] = fmaf(p, vcur, asum[mt][r]);
            }
        }
    }

    const float fr = exp2f((float)(h & 31) * -0.4152410118609203f); // 10000^(-j/32)

    #pragma unroll
    for (int mt = 0; mt < 4; ++mt) {
        #pragma unroll
        for (int r = 0; r < 4; ++r) {
            float ls = lsum[mt][r], as = asum[mt][r];
            ls += __shfl_xor(ls, 1);  as += __shfl_xor(as, 1);
            ls += __shfl_xor(ls, 2);  as += __shfl_xor(as, 2);
            ls += __shfl_xor(ls, 4);  as += __shfl_xor(as, 4);
            ls += __shfl_xor(ls, 8);  as += __shfl_xor(as, 8);
            if (cl == r) {
                const int row = m0w + mt * 16 + g * 4 + r;
                const float pe = (h < 32) ? cosf((float)row * fr)
                                          : sinf((float)row * fr);
                out[((size_t)b * SEQ + row) * DV + h] = as / ls + pe;
            }
        }
    }
}

// ---------------------------------------------------------------------------
extern "C" void kernel_launch(void* const* d_in, const int* in_sizes, int n_in,
                              void* d_out, int out_size, void* d_ws, size_t ws_size,
                              hipStream_t stream)
{
    const float* x  = (const float*)d_in[0];
    const float* Wq = (const float*)d_in[1];
    const float* bq = (const float*)d_in[2];
    const float* Wk = (const float*)d_in[3];
    const float* bk = (const float*)d_in[4];
    const float* Wv = (const float*)d_in[5];
    const float* bv = (const float*)d_in[6];
    float* out = (float*)d_out;

    // ws: Qpk 8MB | Kpk 8MB | Vh 1MB | WtQ 1MB | WtK 1MB | WtV 128KB
    unsigned short* Qpk = (unsigned short*)d_ws;
    unsigned short* Kpk = Qpk + (size_t)BATCH * NH * SEQ * 16;
    float* Vh  = (float*)(Kpk + (size_t)BATCH * NH * SEQ * 16);
    float* WtQ = Vh + (size_t)BATCH * NH * SEQ;
    float* WtK = WtQ + (size_t)DIN * DKQ;
    float* WtV = WtK + (size_t)DIN * DKQ;

    transpose_w<<<dim3(16, 16, 3), dim3(32, 8), 0, stream>>>(Wq, Wk, Wv, WtQ, WtK, WtV);
    proj_kernel<<<dim3(4, 32, 3), 512, 0, stream>>>(x, WtQ, bq, WtK, bk, WtV, bv, Qpk, Kpk, Vh);
    attn_kernel<<<dim3(BATCH * NH, 4), 256, 0, stream>>>(Qpk, Kpk, Vh, out);
}

// Round 4
// 111.568 us; speedup vs baseline: 2.2592x; 1.0561x over previous
//
#include <hip/hip_runtime.h>
#include <math.h>

#define BATCH 4
#define SEQ   1024
#define DIN   512
#define DKQ   512
#define DV    64
#define NH    64

typedef __attribute__((ext_vector_type(8))) short short8v;   // 8 bf16 = 4 VGPRs
typedef __attribute__((ext_vector_type(4))) float float4v;
typedef __attribute__((ext_vector_type(4))) unsigned int uint4v;

__device__ __forceinline__ void split_bf16(float f, unsigned short& hi, unsigned short& lo) {
    unsigned int u = __float_as_uint(f);
    hi = (unsigned short)(u >> 16);
    float l = f - __uint_as_float(u & 0xFFFF0000u);
    lo = (unsigned short)(__float_as_uint(l) >> 16);
}
__device__ __forceinline__ unsigned short f32_to_bf16_rne(float f) {
    unsigned int u = __float_as_uint(f);
    u += 0x7FFFu + ((u >> 16) & 1u);
    return (unsigned short)(u >> 16);
}
__device__ __forceinline__ float bf16_bits_to_f32(unsigned short s) {
    return __uint_as_float((unsigned int)s << 16);
}

// LDS tile: [row 0..127][slot 0..7][8 bf16], slot XOR-swizzled by row (T2)
__device__ __forceinline__ int ldsoff(int r, int sl) {
    return r * 64 + ((sl ^ (r & 7)) << 3);   // ushort units, 16B-aligned
}

// ---------------------------------------------------------------------------
// W transpose pre-pass: Wt[n][k] = W[k][n]
// ---------------------------------------------------------------------------
__global__ __launch_bounds__(256)
void transpose_w(const float* __restrict__ Wq, const float* __restrict__ Wk,
                 const float* __restrict__ Wv,
                 float* __restrict__ WtQ, float* __restrict__ WtK,
                 float* __restrict__ WtV)
{
    const int z = blockIdx.z;
    const int N = (z == 2) ? DV : DKQ;
    if (z == 2 && blockIdx.x >= 2) return;
    const float* __restrict__ W  = (z == 0) ? Wq : (z == 1) ? Wk : Wv;
    float* __restrict__ Wt       = (z == 0) ? WtQ : (z == 1) ? WtK : WtV;

    __shared__ float tile[32][33];
    const int n0 = blockIdx.x * 32, k0 = blockIdx.y * 32;
    const int tx = threadIdx.x, ty = threadIdx.y;
    #pragma unroll
    for (int i = 0; i < 32; i += 8)
        tile[ty + i][tx] = W[(size_t)(k0 + ty + i) * N + n0 + tx];
    __syncthreads();
    #pragma unroll
    for (int i = 0; i < 32; i += 8)
        Wt[(size_t)(n0 + ty + i) * DIN + k0 + tx] = tile[tx][ty + i];
}

// ---------------------------------------------------------------------------
// Projection via MFMA 16x16x32 bf16 hi/lo compensation.
//   z=0: Q -> Qpk[bh][s][0..7]=hi,[8..15]=lo, pre-scaled by 1/sqrt(8)*log2e
//   z=1: K -> Kpk same layout (unscaled)
//   z=2: V -> Vhi/Vlo: u32 of 2 packed bf16 (even s low, odd s high)
// ---------------------------------------------------------------------------
__global__ __launch_bounds__(512)
void proj_kernel(const float* __restrict__ x,
                 const float* __restrict__ WtQ, const float* __restrict__ bq,
                 const float* __restrict__ WtK, const float* __restrict__ bk,
                 const float* __restrict__ WtV, const float* __restrict__ bv,
                 unsigned short* __restrict__ Qpk, unsigned short* __restrict__ Kpk,
                 unsigned int* __restrict__ Vhi, unsigned int* __restrict__ Vlo)
{
    const int z = blockIdx.z;
    if (z == 2 && blockIdx.x != 0) return;
    const float* __restrict__ Wt   = (z == 0) ? WtQ : (z == 1) ? WtK : WtV;
    const float* __restrict__ bias = (z == 0) ? bq : (z == 1) ? bk : bv;

    __shared__ unsigned short As[128 * 64];   // 16 KB
    __shared__ unsigned short Bs[128 * 64];   // 16 KB

    const int t  = threadIdx.x;
    const int bm = blockIdx.y * 128;
    const int bn = blockIdx.x * 128;          // z==2 -> 0

    const int srow = t >> 2;
    const int sg   = t & 3;
    const bool bok = (z != 2) || (srow < 64);

    const int lane = t & 63, wave = t >> 6;
    const int wr = wave >> 2, wc = wave & 3;  // 2x4 wave grid
    const int cl = lane & 15, g2 = lane >> 4;
    const int NF = (z == 2) ? 1 : 2;

    float4v acc[4][2];
    #pragma unroll
    for (int i = 0; i < 4; ++i)
        #pragma unroll
        for (int j = 0; j < 2; ++j)
            acc[i][j] = (float4v){0.f, 0.f, 0.f, 0.f};

    for (int ks = 0; ks < 16; ++ks) {
        const int k0 = ks * 32;
        const float* ap = &x[(size_t)(bm + srow) * DIN + k0 + sg * 8];
        float4 a0 = *(const float4*)(ap);
        float4 a1 = *(const float4*)(ap + 4);
        float4 b0, b1;
        if (bok) {
            const float* bp = &Wt[(size_t)(bn + srow) * DIN + k0 + sg * 8];
            b0 = *(const float4*)(bp);
            b1 = *(const float4*)(bp + 4);
        }
        short8v ahi, alo, bhi, blo;
        {
            float av[8] = {a0.x, a0.y, a0.z, a0.w, a1.x, a1.y, a1.z, a1.w};
            #pragma unroll
            for (int j = 0; j < 8; ++j) {
                unsigned short h, l; split_bf16(av[j], h, l);
                ahi[j] = (short)h; alo[j] = (short)l;
            }
            if (bok) {
                float bvv[8] = {b0.x, b0.y, b0.z, b0.w, b1.x, b1.y, b1.z, b1.w};
                #pragma unroll
                for (int j = 0; j < 8; ++j) {
                    unsigned short h, l; split_bf16(bvv[j], h, l);
                    bhi[j] = (short)h; blo[j] = (short)l;
                }
            }
        }
        __syncthreads();
        *(short8v*)&As[ldsoff(srow, sg * 2)]     = ahi;
        *(short8v*)&As[ldsoff(srow, sg * 2 + 1)] = alo;
        if (bok) {
            *(short8v*)&Bs[ldsoff(srow, sg * 2)]     = bhi;
            *(short8v*)&Bs[ldsoff(srow, sg * 2 + 1)] = blo;
        }
        __syncthreads();

        short8v af_h[4], af_l[4], bf_h[2], bf_l[2];
        #pragma unroll
        for (int mt = 0; mt < 4; ++mt) {
            const int r = wr * 64 + mt * 16 + cl;
            af_h[mt] = *(const short8v*)&As[ldsoff(r, g2 * 2)];
            af_l[mt] = *(const short8v*)&As[ldsoff(r, g2 * 2 + 1)];
        }
        #pragma unroll
        for (int nf = 0; nf < 2; ++nf) {
            if (nf < NF) {
                const int n = wc * (NF * 16) + nf * 16 + cl;
                bf_h[nf] = *(const short8v*)&Bs[ldsoff(n, g2 * 2)];
                bf_l[nf] = *(const short8v*)&Bs[ldsoff(n, g2 * 2 + 1)];
            }
        }
        #pragma unroll
        for (int mt = 0; mt < 4; ++mt)
            #pragma unroll
            for (int nf = 0; nf < 2; ++nf) {
                if (nf >= NF) continue;
                acc[mt][nf] = __builtin_amdgcn_mfma_f32_16x16x32_bf16(af_h[mt], bf_h[nf], acc[mt][nf], 0, 0, 0);
                acc[mt][nf] = __builtin_amdgcn_mfma_f32_16x16x32_bf16(af_l[mt], bf_h[nf], acc[mt][nf], 0, 0, 0);
                acc[mt][nf] = __builtin_amdgcn_mfma_f32_16x16x32_bf16(af_h[mt], bf_l[nf], acc[mt][nf], 0, 0, 0);
            }
    }

    const float cc = 0.35355339059327373f * 1.4426950408889634f;
    if (z == 2) {
        const int n = wc * 16 + cl;   // head
        #pragma unroll
        for (int mt = 0; mt < 4; ++mt) {
            float vv[4]; unsigned short hh[4], ll[4];
            #pragma unroll
            for (int r = 0; r < 4; ++r) {
                vv[r] = fmaxf(acc[mt][0][r] + bias[n], 0.0f);
                hh[r] = f32_to_bf16_rne(vv[r]);
                ll[r] = f32_to_bf16_rne(vv[r] - bf16_bits_to_f32(hh[r]));
            }
            const int row0 = bm + wr * 64 + mt * 16 + g2 * 4;   // even
            const int bb = row0 >> 10, s0 = row0 & 1023;
            size_t base = (size_t)((bb << 6) + n) * (SEQ / 2) + (s0 >> 1);
            Vhi[base]     = (unsigned int)hh[0] | ((unsigned int)hh[1] << 16);
            Vhi[base + 1] = (unsigned int)hh[2] | ((unsigned int)hh[3] << 16);
            Vlo[base]     = (unsigned int)ll[0] | ((unsigned int)ll[1] << 16);
            Vlo[base + 1] = (unsigned int)ll[2] | ((unsigned int)ll[3] << 16);
        }
    } else {
        #pragma unroll
        for (int mt = 0; mt < 4; ++mt) {
            #pragma unroll
            for (int nf = 0; nf < 2; ++nf) {
                #pragma unroll
                for (int r = 0; r < 4; ++r) {
                    const int row = bm + wr * 64 + mt * 16 + g2 * 4 + r;
                    const int bb = row >> 10, s = row & 1023;
                    const int n = bn + wc * 32 + nf * 16 + cl;
                    float val = fmaxf(acc[mt][nf][r] + bias[n], 0.0f);
                    if (z == 0) val *= cc;
                    const int hh2 = n >> 3, d = n & 7;
                    unsigned short* dst = (z == 0) ? Qpk : Kpk;
                    size_t base = ((size_t)((bb << 6) + hh2) * SEQ + s) * 16 + d;
                    unsigned short hi = f32_to_bf16_rne(val);
                    dst[base]     = hi;
                    dst[base + 8] = f32_to_bf16_rne(val - bf16_bits_to_f32(hi));
                }
            }
        }
    }
}

// ---------------------------------------------------------------------------
// Attention, swapped-operand form:
//   S^T tile = mfma(A=K_frag, B=Q_frag): lane cl = query, regs = keys g*4+r.
//   p = exp2(s) (Q pre-scaled). p truncated to bf16 (v_perm), placed in the
//   zero-padded B-operand of a second 16x16x32 MFMA whose A rows are
//   {v_hi, ones, v_lo, 0...} -> C row0=num_hi, row1=den, row2=num_lo,
//   accumulated over the block's 32 key-tiles. Split-K 2-way; partials to ws.
// ---------------------------------------------------------------------------
__global__ __launch_bounds__(256, 6)
void attn_kernel(const unsigned short* __restrict__ Qpk,
                 const unsigned short* __restrict__ Kpk,
                 const unsigned int* __restrict__ Vhi,
                 const unsigned int* __restrict__ Vlo,
                 float2* __restrict__ part)
{
    const int bh = blockIdx.x;          // b*64 + h
    const int yb = blockIdx.y;          // 0..7
    const int qchunk = yb >> 1;         // 0..3
    const int half = yb & 1;            // key half
    const int t = threadIdx.x;
    const int wave = t >> 6, lane = t & 63;
    const int g = lane >> 4, cl = lane & 15;

    const unsigned short* __restrict__ qb = Qpk + (size_t)bh * SEQ * 16;
    const unsigned short* __restrict__ kb = Kpk + (size_t)bh * SEQ * 16;
    const unsigned int* __restrict__ vhb = Vhi + (size_t)bh * (SEQ / 2);
    const unsigned int* __restrict__ vlb = Vlo + (size_t)bh * (SEQ / 2);

    const int q0 = qchunk * 256 + wave * 64;

    // B(Q) fragments: col=cl=query; slots g0=hi, g1=lo, g2=hi, g3=0
    short8v bq[4];
    #pragma unroll
    for (int qt = 0; qt < 4; ++qt) {
        if (g == 3) { short8v zz = {0,0,0,0,0,0,0,0}; bq[qt] = zz; }
        else bq[qt] = *(const short8v*)(qb + (size_t)(q0 + qt * 16 + cl) * 16 + ((g == 1) ? 8 : 0));
    }

    const int koff = (g >> 1) * 8;      // A(K): g0,g1=hi; g2=lo; g3=lo (junk, B=0)
    const unsigned int ONES = 0x3F803F80u;
    const float4v c0 = {0.f, 0.f, 0.f, 0.f};

    float4v acc[4];
    #pragma unroll
    for (int qt = 0; qt < 4; ++qt) acc[qt] = c0;

    const int nt0 = half * 32;
    short8v kf = *(const short8v*)(kb + (size_t)(nt0 * 16 + cl) * 16 + koff);
    unsigned int vh0 = vhb[nt0 * 8 + g * 2], vh1 = vhb[nt0 * 8 + g * 2 + 1];
    unsigned int vl0 = vlb[nt0 * 8 + g * 2], vl1 = vlb[nt0 * 8 + g * 2 + 1];

    for (int nt = nt0; nt < nt0 + 32; ++nt) {
        const short8v kfc = kf;
        const unsigned int ch0 = vh0, ch1 = vh1, cll0 = vl0, cll1 = vl1;
        if (nt < nt0 + 31) {
            kf = *(const short8v*)(kb + (size_t)((nt + 1) * 16 + cl) * 16 + koff);
            vh0 = vhb[(nt + 1) * 8 + g * 2]; vh1 = vhb[(nt + 1) * 8 + g * 2 + 1];
            vl0 = vlb[(nt + 1) * 8 + g * 2]; vl1 = vlb[(nt + 1) * 8 + g * 2 + 1];
        }
        // A(v/ones) fragment: row(cl)0=v_hi, 1=ones, 2=v_lo, else 0; slots j>=4 zero
        const unsigned int a0 = (cl == 0) ? ch0 : (cl == 1) ? ONES : (cl == 2) ? cll0 : 0u;
        const unsigned int a1 = (cl == 0) ? ch1 : (cl == 1) ? ONES : (cl == 2) ? cll1 : 0u;
        uint4v au = {a0, a1, 0u, 0u};
        const short8v af = __builtin_bit_cast(short8v, au);

        #pragma unroll
        for (int qt = 0; qt < 4; ++qt) {
            float4v st = __builtin_amdgcn_mfma_f32_16x16x32_bf16(kfc, bq[qt], c0, 0, 0, 0);
            float p0 = exp2f(st[0]), p1 = exp2f(st[1]);
            float p2 = exp2f(st[2]), p3 = exp2f(st[3]);
            // truncate-pack pairs to bf16 (1 v_perm each); softmax ratio cancels bias
            unsigned int pk0 = __builtin_amdgcn_perm(__float_as_uint(p1), __float_as_uint(p0), 0x07060302u);
            unsigned int pk1 = __builtin_amdgcn_perm(__float_as_uint(p3), __float_as_uint(p2), 0x07060302u);
            uint4v pu = {pk0, pk1, 0u, 0u};
            acc[qt] = __builtin_amdgcn_mfma_f32_16x16x32_bf16(af, __builtin_bit_cast(short8v, pu), acc[qt], 0, 0, 0);
        }
    }

    if (g == 0) {
        #pragma unroll
        for (int qt = 0; qt < 4; ++qt) {
            const int row = q0 + qt * 16 + cl;
            float2 pr;
            pr.x = acc[qt][0] + acc[qt][2];   // numerator (v_hi + v_lo parts)
            pr.y = acc[qt][1];                // denominator
            part[(size_t)(half * 256 + bh) * SEQ + row] = pr;
        }
    }
}

// ---------------------------------------------------------------------------
// Merge split-K halves + positional embedding. h-fastest for coalesced out.
// ---------------------------------------------------------------------------
__global__ __launch_bounds__(256)
void merge_kernel(const float2* __restrict__ part, float* __restrict__ out)
{
    const int tid = blockIdx.x * 256 + threadIdx.x;  // = (b*1024+q)*64+h
    const int h = tid & 63;
    const int q = (tid >> 6) & 1023;
    const int b = tid >> 16;
    const int bh = (b << 6) + h;
    float2 p0 = part[(size_t)bh * SEQ + q];
    float2 p1 = part[(size_t)(256 + bh) * SEQ + q];
    const float fr = exp2f((float)(h & 31) * -0.4152410118609203f); // 10000^(-j/32)
    const float pe = (h < 32) ? cosf((float)q * fr) : sinf((float)q * fr);
    out[tid] = (p0.x + p1.x) / (p0.y + p1.y) + pe;
}

// ---------------------------------------------------------------------------
extern "C" void kernel_launch(void* const* d_in, const int* in_sizes, int n_in,
                              void* d_out, int out_size, void* d_ws, size_t ws_size,
                              hipStream_t stream)
{
    const float* x  = (const float*)d_in[0];
    const float* Wq = (const float*)d_in[1];
    const float* bq = (const float*)d_in[2];
    const float* Wk = (const float*)d_in[3];
    const float* bk = (const float*)d_in[4];
    const float* Wv = (const float*)d_in[5];
    const float* bv = (const float*)d_in[6];
    float* out = (float*)d_out;

    // ws: Qpk 8MB | Kpk 8MB | Vhi 512KB | Vlo 512KB | X: Wt (2.125MB) aliased
    // with part (4MB) -- Wt live only through proj, part only after. ~21MB.
    unsigned short* Qpk = (unsigned short*)d_ws;
    unsigned short* Kpk = Qpk + (size_t)BATCH * NH * SEQ * 16;
    unsigned int* Vhi = (unsigned int*)(Kpk + (size_t)BATCH * NH * SEQ * 16);
    unsigned int* Vlo = Vhi + (size_t)BATCH * NH * (SEQ / 2);
    char* xbase = (char*)(Vlo + (size_t)BATCH * NH * (SEQ / 2));
    float* WtQ = (float*)xbase;
    float* WtK = WtQ + (size_t)DIN * DKQ;
    float* WtV = WtK + (size_t)DIN * DKQ;
    float2* part = (float2*)xbase;   // overwrites Wt after proj completes

    transpose_w<<<dim3(16, 16, 3), dim3(32, 8), 0, stream>>>(Wq, Wk, Wv, WtQ, WtK, WtV);
    proj_kernel<<<dim3(4, 32, 3), 512, 0, stream>>>(x, WtQ, bq, WtK, bk, WtV, bv, Qpk, Kpk, Vhi, Vlo);
    attn_kernel<<<dim3(256, 8), 256, 0, stream>>>(Qpk, Kpk, Vhi, Vlo, part);
    merge_kernel<<<dim3((BATCH * SEQ * DV) / 256), 256, 0, stream>>>(part, out);
}

// Round 5
// 86.179 us; speedup vs baseline: 2.9247x; 1.2946x over previous
//
#include <hip/hip_runtime.h>
#include <math.h>

#define BATCH 4
#define SEQ   1024
#define DIN   512
#define DKQ   512
#define DV    64
#define NH    64

typedef __attribute__((ext_vector_type(8))) short short8v;   // 8 bf16 = 4 VGPRs
typedef __attribute__((ext_vector_type(4))) float float4v;
typedef __attribute__((ext_vector_type(4))) unsigned int uint4v;

__device__ __forceinline__ void split_bf16(float f, unsigned short& hi, unsigned short& lo) {
    unsigned int u = __float_as_uint(f);
    hi = (unsigned short)(u >> 16);
    float l = f - __uint_as_float(u & 0xFFFF0000u);
    lo = (unsigned short)(__float_as_uint(l) >> 16);
}
__device__ __forceinline__ unsigned short f32_to_bf16_rne(float f) {
    unsigned int u = __float_as_uint(f);
    u += 0x7FFFu + ((u >> 16) & 1u);
    return (unsigned short)(u >> 16);
}
__device__ __forceinline__ float bf16_bits_to_f32(unsigned short s) {
    return __uint_as_float((unsigned int)s << 16);
}

// LDS tile: [row 0..127][slot 0..7][8 bf16], slot XOR-swizzled by row (T2)
__device__ __forceinline__ int ldsoff(int r, int sl) {
    return r * 64 + ((sl ^ (r & 7)) << 3);   // ushort units, 16B-aligned
}

// ---------------------------------------------------------------------------
// x pre-pack: f32 -> bf16 hi/lo planes (done ONCE instead of 9x inside proj)
// ---------------------------------------------------------------------------
__global__ __launch_bounds__(256)
void pack_x(const float* __restrict__ x,
            unsigned short* __restrict__ Xhi, unsigned short* __restrict__ Xlo)
{
    const int i = (blockIdx.x * 256 + threadIdx.x) * 8;
    float4 a0 = *(const float4*)&x[i];
    float4 a1 = *(const float4*)&x[i + 4];
    float av[8] = {a0.x, a0.y, a0.z, a0.w, a1.x, a1.y, a1.z, a1.w};
    short8v h, l;
    #pragma unroll
    for (int j = 0; j < 8; ++j) {
        unsigned short hh, ll; split_bf16(av[j], hh, ll);
        h[j] = (short)hh; l[j] = (short)ll;
    }
    *(short8v*)&Xhi[i] = h;
    *(short8v*)&Xlo[i] = l;
}

// ---------------------------------------------------------------------------
// W transpose + pack pre-pass: Whi/Wlo[n][k] = bf16 hi/lo of W[k][n]
// ---------------------------------------------------------------------------
__global__ __launch_bounds__(256)
void transpose_w(const float* __restrict__ Wq, const float* __restrict__ Wk,
                 const float* __restrict__ Wv,
                 unsigned short* __restrict__ WhiQ, unsigned short* __restrict__ WloQ,
                 unsigned short* __restrict__ WhiK, unsigned short* __restrict__ WloK,
                 unsigned short* __restrict__ WhiV, unsigned short* __restrict__ WloV)
{
    const int z = blockIdx.z;
    const int N = (z == 2) ? DV : DKQ;
    if (z == 2 && blockIdx.x >= 2) return;
    const float* __restrict__ W = (z == 0) ? Wq : (z == 1) ? Wk : Wv;
    unsigned short* __restrict__ Whi = (z == 0) ? WhiQ : (z == 1) ? WhiK : WhiV;
    unsigned short* __restrict__ Wlo = (z == 0) ? WloQ : (z == 1) ? WloK : WloV;

    __shared__ float tile[32][33];
    const int n0 = blockIdx.x * 32, k0 = blockIdx.y * 32;
    const int tx = threadIdx.x, ty = threadIdx.y;
    #pragma unroll
    for (int i = 0; i < 32; i += 8)
        tile[ty + i][tx] = W[(size_t)(k0 + ty + i) * N + n0 + tx];
    __syncthreads();
    #pragma unroll
    for (int i = 0; i < 32; i += 8) {
        unsigned short h, l; split_bf16(tile[tx][ty + i], h, l);
        Whi[(size_t)(n0 + ty + i) * DIN + k0 + tx] = h;
        Wlo[(size_t)(n0 + ty + i) * DIN + k0 + tx] = l;
    }
}

// ---------------------------------------------------------------------------
// Projection via MFMA 16x16x32 bf16 hi/lo compensation; operands pre-packed.
//   z=0: Q -> Qpk[bh][s][0..7]=hi,[8..15]=lo, pre-scaled by 1/sqrt(8)*log2e
//   z=1: K -> Kpk same layout (unscaled)
//   z=2: V -> Vhi/Vlo: u32 of 2 packed bf16 (even s low, odd s high)
// ---------------------------------------------------------------------------
__global__ __launch_bounds__(512)
void proj_kernel(const unsigned short* __restrict__ Xhi,
                 const unsigned short* __restrict__ Xlo,
                 const unsigned short* __restrict__ WhiQ, const unsigned short* __restrict__ WloQ,
                 const float* __restrict__ bq,
                 const unsigned short* __restrict__ WhiK, const unsigned short* __restrict__ WloK,
                 const float* __restrict__ bk,
                 const unsigned short* __restrict__ WhiV, const unsigned short* __restrict__ WloV,
                 const float* __restrict__ bv,
                 unsigned short* __restrict__ Qpk, unsigned short* __restrict__ Kpk,
                 unsigned int* __restrict__ Vhi, unsigned int* __restrict__ Vlo)
{
    const int z = blockIdx.z;
    if (z == 2 && blockIdx.x != 0) return;
    const unsigned short* __restrict__ Whi = (z == 0) ? WhiQ : (z == 1) ? WhiK : WhiV;
    const unsigned short* __restrict__ Wlo = (z == 0) ? WloQ : (z == 1) ? WloK : WloV;
    const float* __restrict__ bias = (z == 0) ? bq : (z == 1) ? bk : bv;

    __shared__ unsigned short As[128 * 64];   // 16 KB
    __shared__ unsigned short Bs[128 * 64];   // 16 KB

    const int t  = threadIdx.x;
    const int bm = blockIdx.y * 128;
    const int bn = blockIdx.x * 128;          // z==2 -> 0

    const int srow = t >> 2;
    const int sg   = t & 3;
    const bool bok = (z != 2) || (srow < 64);

    const int lane = t & 63, wave = t >> 6;
    const int wr = wave >> 2, wc = wave & 3;  // 2x4 wave grid
    const int cl = lane & 15, g2 = lane >> 4;
    const int NF = (z == 2) ? 1 : 2;

    float4v acc[4][2];
    #pragma unroll
    for (int i = 0; i < 4; ++i)
        #pragma unroll
        for (int j = 0; j < 2; ++j)
            acc[i][j] = (float4v){0.f, 0.f, 0.f, 0.f};

    for (int ks = 0; ks < 16; ++ks) {
        const int k0 = ks * 32;
        const size_t ao = (size_t)(bm + srow) * DIN + k0 + sg * 8;
        short8v ahi = *(const short8v*)(Xhi + ao);
        short8v alo = *(const short8v*)(Xlo + ao);
        short8v bhi, blo;
        if (bok) {
            const size_t bo = (size_t)(bn + srow) * DIN + k0 + sg * 8;
            bhi = *(const short8v*)(Whi + bo);
            blo = *(const short8v*)(Wlo + bo);
        }
        __syncthreads();   // previous iteration's LDS reads complete
        *(short8v*)&As[ldsoff(srow, sg * 2)]     = ahi;
        *(short8v*)&As[ldsoff(srow, sg * 2 + 1)] = alo;
        if (bok) {
            *(short8v*)&Bs[ldsoff(srow, sg * 2)]     = bhi;
            *(short8v*)&Bs[ldsoff(srow, sg * 2 + 1)] = blo;
        }
        __syncthreads();

        short8v af_h[4], af_l[4], bf_h[2], bf_l[2];
        #pragma unroll
        for (int mt = 0; mt < 4; ++mt) {
            const int r = wr * 64 + mt * 16 + cl;
            af_h[mt] = *(const short8v*)&As[ldsoff(r, g2 * 2)];
            af_l[mt] = *(const short8v*)&As[ldsoff(r, g2 * 2 + 1)];
        }
        #pragma unroll
        for (int nf = 0; nf < 2; ++nf) {
            if (nf < NF) {
                const int n = wc * (NF * 16) + nf * 16 + cl;
                bf_h[nf] = *(const short8v*)&Bs[ldsoff(n, g2 * 2)];
                bf_l[nf] = *(const short8v*)&Bs[ldsoff(n, g2 * 2 + 1)];
            }
        }
        #pragma unroll
        for (int mt = 0; mt < 4; ++mt)
            #pragma unroll
            for (int nf = 0; nf < 2; ++nf) {
                if (nf >= NF) continue;
                acc[mt][nf] = __builtin_amdgcn_mfma_f32_16x16x32_bf16(af_h[mt], bf_h[nf], acc[mt][nf], 0, 0, 0);
                acc[mt][nf] = __builtin_amdgcn_mfma_f32_16x16x32_bf16(af_l[mt], bf_h[nf], acc[mt][nf], 0, 0, 0);
                acc[mt][nf] = __builtin_amdgcn_mfma_f32_16x16x32_bf16(af_h[mt], bf_l[nf], acc[mt][nf], 0, 0, 0);
            }
    }

    const float cc = 0.35355339059327373f * 1.4426950408889634f;
    if (z == 2) {
        const int n = wc * 16 + cl;   // head
        #pragma unroll
        for (int mt = 0; mt < 4; ++mt) {
            float vv[4]; unsigned short hh[4], ll[4];
            #pragma unroll
            for (int r = 0; r < 4; ++r) {
                vv[r] = fmaxf(acc[mt][0][r] + bias[n], 0.0f);
                hh[r] = f32_to_bf16_rne(vv[r]);
                ll[r] = f32_to_bf16_rne(vv[r] - bf16_bits_to_f32(hh[r]));
            }
            const int row0 = bm + wr * 64 + mt * 16 + g2 * 4;   // even
            const int bb = row0 >> 10, s0 = row0 & 1023;
            size_t base = (size_t)((bb << 6) + n) * (SEQ / 2) + (s0 >> 1);
            Vhi[base]     = (unsigned int)hh[0] | ((unsigned int)hh[1] << 16);
            Vhi[base + 1] = (unsigned int)hh[2] | ((unsigned int)hh[3] << 16);
            Vlo[base]     = (unsigned int)ll[0] | ((unsigned int)ll[1] << 16);
            Vlo[base + 1] = (unsigned int)ll[2] | ((unsigned int)ll[3] << 16);
        }
    } else {
        #pragma unroll
        for (int mt = 0; mt < 4; ++mt) {
            #pragma unroll
            for (int nf = 0; nf < 2; ++nf) {
                #pragma unroll
                for (int r = 0; r < 4; ++r) {
                    const int row = bm + wr * 64 + mt * 16 + g2 * 4 + r;
                    const int bb = row >> 10, s = row & 1023;
                    const int n = bn + wc * 32 + nf * 16 + cl;
                    float val = fmaxf(acc[mt][nf][r] + bias[n], 0.0f);
                    if (z == 0) val *= cc;
                    const int hh2 = n >> 3, d = n & 7;
                    unsigned short* dst = (z == 0) ? Qpk : Kpk;
                    size_t base = ((size_t)((bb << 6) + hh2) * SEQ + s) * 16 + d;
                    unsigned short hi = f32_to_bf16_rne(val);
                    dst[base]     = hi;
                    dst[base + 8] = f32_to_bf16_rne(val - bf16_bits_to_f32(hi));
                }
            }
        }
    }
}

// ---------------------------------------------------------------------------
// Attention, swapped-operand form, split-K 4-way. p = raw v_exp_f32 (inputs
// bounded, wrapper-free). PV+denominator via zero-padded second MFMA.
// ---------------------------------------------------------------------------
__global__ __launch_bounds__(256, 6)
void attn_kernel(const unsigned short* __restrict__ Qpk,
                 const unsigned short* __restrict__ Kpk,
                 const unsigned int* __restrict__ Vhi,
                 const unsigned int* __restrict__ Vlo,
                 float2* __restrict__ part)
{
    const int bh = blockIdx.x;          // b*64 + h
    const int yb = blockIdx.y;          // 0..15
    const int qchunk = yb >> 2;         // 0..3
    const int kq = yb & 3;              // key quarter
    const int t = threadIdx.x;
    const int wave = t >> 6, lane = t & 63;
    const int g = lane >> 4, cl = lane & 15;

    const unsigned short* __restrict__ qb = Qpk + (size_t)bh * SEQ * 16;
    const unsigned short* __restrict__ kb = Kpk + (size_t)bh * SEQ * 16;
    const unsigned int* __restrict__ vhb = Vhi + (size_t)bh * (SEQ / 2);
    const unsigned int* __restrict__ vlb = Vlo + (size_t)bh * (SEQ / 2);

    const int q0 = qchunk * 256 + wave * 64;

    // B(Q) fragments: col=cl=query; slots g0=hi, g1=lo, g2=hi, g3=0
    short8v bq[4];
    #pragma unroll
    for (int qt = 0; qt < 4; ++qt) {
        if (g == 3) { short8v zz = {0,0,0,0,0,0,0,0}; bq[qt] = zz; }
        else bq[qt] = *(const short8v*)(qb + (size_t)(q0 + qt * 16 + cl) * 16 + ((g == 1) ? 8 : 0));
    }

    const int koff = (g >> 1) * 8;      // A(K): g0,g1=hi; g2=lo; g3=lo (junk, B=0)
    const unsigned int ONES = 0x3F803F80u;
    const float4v c0 = {0.f, 0.f, 0.f, 0.f};

    float4v acc[4];
    #pragma unroll
    for (int qt = 0; qt < 4; ++qt) acc[qt] = c0;

    const int nt0 = kq * 16;
    short8v kf = *(const short8v*)(kb + (size_t)(nt0 * 16 + cl) * 16 + koff);
    unsigned int vh0 = vhb[nt0 * 8 + g * 2], vh1 = vhb[nt0 * 8 + g * 2 + 1];
    unsigned int vl0 = vlb[nt0 * 8 + g * 2], vl1 = vlb[nt0 * 8 + g * 2 + 1];

    for (int nt = nt0; nt < nt0 + 16; ++nt) {
        const short8v kfc = kf;
        const unsigned int ch0 = vh0, ch1 = vh1, cll0 = vl0, cll1 = vl1;
        if (nt < nt0 + 15) {
            kf = *(const short8v*)(kb + (size_t)((nt + 1) * 16 + cl) * 16 + koff);
            vh0 = vhb[(nt + 1) * 8 + g * 2]; vh1 = vhb[(nt + 1) * 8 + g * 2 + 1];
            vl0 = vlb[(nt + 1) * 8 + g * 2]; vl1 = vlb[(nt + 1) * 8 + g * 2 + 1];
        }
        // A(v/ones) fragment: row(cl)0=v_hi, 1=ones, 2=v_lo, else 0; slots j>=4 zero
        const unsigned int a0 = (cl == 0) ? ch0 : (cl == 1) ? ONES : (cl == 2) ? cll0 : 0u;
        const unsigned int a1 = (cl == 0) ? ch1 : (cl == 1) ? ONES : (cl == 2) ? cll1 : 0u;
        uint4v au = {a0, a1, 0u, 0u};
        const short8v af = __builtin_bit_cast(short8v, au);

        #pragma unroll
        for (int qt = 0; qt < 4; ++qt) {
            float4v st = __builtin_amdgcn_mfma_f32_16x16x32_bf16(kfc, bq[qt], c0, 0, 0, 0);
            float p0 = __builtin_amdgcn_exp2f(st[0]);
            float p1 = __builtin_amdgcn_exp2f(st[1]);
            float p2 = __builtin_amdgcn_exp2f(st[2]);
            float p3 = __builtin_amdgcn_exp2f(st[3]);
            // truncate-pack pairs to bf16 (1 v_perm each); softmax ratio cancels bias
            unsigned int pk0 = __builtin_amdgcn_perm(__float_as_uint(p1), __float_as_uint(p0), 0x07060302u);
            unsigned int pk1 = __builtin_amdgcn_perm(__float_as_uint(p3), __float_as_uint(p2), 0x07060302u);
            uint4v pu = {pk0, pk1, 0u, 0u};
            acc[qt] = __builtin_amdgcn_mfma_f32_16x16x32_bf16(af, __builtin_bit_cast(short8v, pu), acc[qt], 0, 0, 0);
        }
    }

    if (g == 0) {
        #pragma unroll
        for (int qt = 0; qt < 4; ++qt) {
            const int row = q0 + qt * 16 + cl;
            float2 pr;
            pr.x = acc[qt][0] + acc[qt][2];   // numerator (v_hi + v_lo parts)
            pr.y = acc[qt][1];                // denominator
            part[(size_t)(kq * 256 + bh) * SEQ + row] = pr;
        }
    }
}

// ---------------------------------------------------------------------------
// Merge split-K quarters + positional embedding. h-fastest coalesced out.
// ---------------------------------------------------------------------------
__global__ __launch_bounds__(256)
void merge_kernel(const float2* __restrict__ part, float* __restrict__ out)
{
    const int tid = blockIdx.x * 256 + threadIdx.x;  // = (b*1024+q)*64+h
    const int h = tid & 63;
    const int q = (tid >> 6) & 1023;
    const int b = tid >> 16;
    const int bh = (b << 6) + h;
    float num = 0.f, den = 0.f;
    #pragma unroll
    for (int kq = 0; kq < 4; ++kq) {
        float2 p = part[(size_t)(kq * 256 + bh) * SEQ + q];
        num += p.x; den += p.y;
    }
    const float fr = __builtin_amdgcn_exp2f((float)(h & 31) * -0.4152410118609203f);
    const float pe = (h < 32) ? cosf((float)q * fr) : sinf((float)q * fr);
    out[tid] = num / den + pe;
}

// ---------------------------------------------------------------------------
extern "C" void kernel_launch(void* const* d_in, const int* in_sizes, int n_in,
                              void* d_out, int out_size, void* d_ws, size_t ws_size,
                              hipStream_t stream)
{
    const float* x  = (const float*)d_in[0];
    const float* Wq = (const float*)d_in[1];
    const float* bq = (const float*)d_in[2];
    const float* Wk = (const float*)d_in[3];
    const float* bk = (const float*)d_in[4];
    const float* Wv = (const float*)d_in[5];
    const float* bv = (const float*)d_in[6];
    float* out = (float*)d_out;

    // ws: Qpk 8MB | Kpk 8MB | Vhi .5 | Vlo .5 | X/part 8MB (aliased) | Wpk 2.125MB
    unsigned short* Qpk = (unsigned short*)d_ws;
    unsigned short* Kpk = Qpk + (size_t)BATCH * NH * SEQ * 16;
    unsigned int* Vhi = (unsigned int*)(Kpk + (size_t)BATCH * NH * SEQ * 16);
    unsigned int* Vlo = Vhi + (size_t)BATCH * NH * (SEQ / 2);
    unsigned short* Xhi = (unsigned short*)(Vlo + (size_t)BATCH * NH * (SEQ / 2));
    unsigned short* Xlo = Xhi + (size_t)BATCH * SEQ * DIN;
    float2* part = (float2*)Xhi;   // aliases X planes: X dead after proj
    unsigned short* WhiQ = Xlo + (size_t)BATCH * SEQ * DIN;
    unsigned short* WloQ = WhiQ + (size_t)DIN * DKQ;
    unsigned short* WhiK = WloQ + (size_t)DIN * DKQ;
    unsigned short* WloK = WhiK + (size_t)DIN * DKQ;
    unsigned short* WhiV = WloK + (size_t)DIN * DKQ;
    unsigned short* WloV = WhiV + (size_t)DIN * DV;

    pack_x<<<dim3((BATCH * SEQ * DIN) / (8 * 256)), 256, 0, stream>>>(x, Xhi, Xlo);
    transpose_w<<<dim3(16, 16, 3), dim3(32, 8), 0, stream>>>(
        Wq, Wk, Wv, WhiQ, WloQ, WhiK, WloK, WhiV, WloV);
    proj_kernel<<<dim3(4, 32, 3), 512, 0, stream>>>(
        Xhi, Xlo, WhiQ, WloQ, bq, WhiK, WloK, bk, WhiV, WloV, bv, Qpk, Kpk, Vhi, Vlo);
    attn_kernel<<<dim3(256, 16), 256, 0, stream>>>(Qpk, Kpk, Vhi, Vlo, part);
    merge_kernel<<<dim3((BATCH * SEQ * DV) / 256), 256, 0, stream>>>(part, out);
}